// Round 11
// baseline (810.921 us; speedup 1.0000x reference)
//
#include <hip/hip_runtime.h>
#include <hip/hip_bf16.h>
#include <math.h>

#define NN 25000
#define NE 250000
#define DD 64
#define HH 4
#define NGROUP (NE / 16)   // 15625 16-edge groups
#define NB 98              // (kept for ws layout compat)

typedef __attribute__((ext_vector_type(8))) short bf16x8;
typedef __attribute__((ext_vector_type(4))) float f32x4;

#define WT_LD 136   // 128 + 8 pad (shorts) -> 272B row stride, 2-way LDS conflict (free)

__device__ __forceinline__ float softplus_f(float x) {
    return fmaxf(x, 0.0f) + __logf(1.0f + __expf(-fabsf(x)));
}

__device__ __forceinline__ unsigned short f2bf(float f) {
    __hip_bfloat16 h = __float2bfloat16(f);
    unsigned short u;
    __builtin_memcpy(&u, &h, 2);
    return u;
}

__device__ __forceinline__ float bf2f(unsigned short u) {
    return __uint_as_float(((unsigned int)u) << 16);
}

// Load 8 consecutive floats, split each into bf16 hi + bf16 lo (compensated).
__device__ __forceinline__ void load8(const float* p, bf16x8& hi, bf16x8& lo) {
    float4 a = *(const float4*)p;
    float4 b = *(const float4*)(p + 4);
    float v[8] = {a.x, a.y, a.z, a.w, b.x, b.y, b.z, b.w};
#pragma unroll
    for (int i = 0; i < 8; ++i) {
        unsigned short h = f2bf(v[i]);
        hi[i] = (short)h;
        lo[i] = (short)f2bf(v[i] - bf2f(h));
    }
}

// ===== k_edge: r9 body (172us measured), block 512 -> 1024 =====
// LDS (71680B) caps at 2 blocks/CU no matter the block size, so 1024-thread
// blocks double resident waves: 2 x 16 = 32 waves/CU (100%) vs 16 at 512.
// VGPR measured 64 under (512,4); (1024,8) pins that same 64-reg cap.
// Kernel is LATENCY-bound (per-SIMD VALU issue ~20%; CU-level VALUBusy 62%
// is an any-SIMD OR) -> occupancy is the lever.
// TRIPWIRES (r3/r7/r10 lessons): VGPR must be 64 and FETCH ~165MB; if VGPR
// >64 or FETCH balloons -> spill -> revert. x-GEMV hoisting (r10) FETCHes
// 406MB of scattered xW reads -> never again.
__global__ __launch_bounds__(1024, 8)
void k_edge(const float* __restrict__ x, const float* __restrict__ ea,
            const float* __restrict__ W, const float* __restrict__ att,
            const float* __restrict__ bn_g, const float* __restrict__ bn_b,
            const float* __restrict__ bn_m, const float* __restrict__ bn_v,
            const int* __restrict__ eidx, const int* __restrict__ perm,
            unsigned short* __restrict__ outj,
            float* __restrict__ expa, float* __restrict__ denom)
{
    __shared__ unsigned short Wsh[256 * WT_LD];  // W^T bf16 [n][k], padded
    __shared__ float attI[256], attJ[256];

    const int tid = threadIdx.x;
    const int lane = tid & 63;
    const int q = lane >> 4;      // quad 0..3
    const int r = lane & 15;

    // Stage W^T (coalesced read of W[k*256+n], n fast-varying).
    for (int idx = tid; idx < 32768; idx += 1024) {
        int k = idx >> 8, n = idx & 255;
        Wsh[n * WT_LD + k] = f2bf(W[idx]);
    }
    if (tid < 256) {
        int c = tid;
        attI[c] = att[(c >> 6) * 128 + (c & 63)];
        attJ[c] = att[(c >> 6) * 128 + 64 + (c & 63)];
    }
    float bnsc[HH], bnsh[HH];
#pragma unroll
    for (int t = 0; t < HH; ++t) {
        float inv = rsqrtf(bn_v[t] + 1e-5f);
        bnsc[t] = bn_g[t] * inv;
        bnsh[t] = bn_b[t] - bn_m[t] * bn_g[t] * inv;
    }
    __syncthreads();

    const int gw = blockIdx.x * 16 + (tid >> 6);
    const int nw = gridDim.x * 16;

    for (int g = gw; g < NGROUP; g += nw) {
        const int e0 = g * 16;                 // sorted-position base
        const int pe = perm[e0 + r];           // edge id at this position
        const int ei = eidx[pe];               // target node (sorted-clustered)
        const int ej = eidx[NE + pe];
        const float* xi = x + (size_t)ei * DD;
        const float* xj = x + (size_t)ej * DD;
        const float* ev = ea + (size_t)pe * DD;

        bf16x8 Ahi[6], Alo[6];  // 0,1: x_i k-tiles; 2,3: x_j; 4,5: ea
        load8(xi + q * 8,      Ahi[0], Alo[0]);
        load8(xi + 32 + q * 8, Ahi[1], Alo[1]);
        load8(xj + q * 8,      Ahi[2], Alo[2]);
        load8(xj + 32 + q * 8, Ahi[3], Alo[3]);
        load8(ev + q * 8,      Ahi[4], Alo[4]);
        load8(ev + 32 + q * 8, Ahi[5], Alo[5]);

        float lg[4][4];  // [reg][head]
#pragma unroll
        for (int a = 0; a < 4; ++a)
#pragma unroll
            for (int b = 0; b < 4; ++b) lg[a][b] = 0.f;

        // ---- fused MFMA + epilogue: iteration nt handles col-tiles
        // {nt+4h | h=0..3} (one col per head per lane -> one ushort4 store) ----
#pragma unroll
        for (int nt = 0; nt < 4; ++nt) {
            f32x4 ai[4], aj[4];
#pragma unroll
            for (int h = 0; h < 4; ++h) {
                ai[h] = (f32x4){0.f, 0.f, 0.f, 0.f};
                aj[h] = (f32x4){0.f, 0.f, 0.f, 0.f};
            }
#pragma unroll
            for (int h = 0; h < 4; ++h) {
                const unsigned short* bp = &Wsh[((nt + 4 * h) * 16 + r) * WT_LD + q * 8];
#pragma unroll
                for (int kt = 0; kt < 4; ++kt) {
                    bf16x8 bf = *(const bf16x8*)(bp + kt * 32);
                    const int fi = (kt < 2) ? kt : kt + 2;  // x_i, x_i, ea, ea
                    const int fj = kt + 2;                  // x_j, x_j, ea, ea
                    ai[h] = __builtin_amdgcn_mfma_f32_16x16x32_bf16(Ahi[fi], bf, ai[h], 0, 0, 0);
                    ai[h] = __builtin_amdgcn_mfma_f32_16x16x32_bf16(Alo[fi], bf, ai[h], 0, 0, 0);
                    aj[h] = __builtin_amdgcn_mfma_f32_16x16x32_bf16(Ahi[fj], bf, aj[h], 0, 0, 0);
                    aj[h] = __builtin_amdgcn_mfma_f32_16x16x32_bf16(Alo[fj], bf, aj[h], 0, 0, 0);
                }
            }
            // consume: softplus, att partials, pack+store outj (acc dies here)
            const int dbase = nt * 16 + r;   // dim index d for this lane
#pragma unroll
            for (int reg = 0; reg < 4; ++reg) {
                ushort4 pk;
                unsigned short* pkp = (unsigned short*)&pk;
#pragma unroll
                for (int h = 0; h < 4; ++h) {
                    const int c = dbase + 64 * h;
                    float spi = softplus_f(ai[h][reg]);
                    float spj = softplus_f(aj[h][reg]);
                    lg[reg][h] += spi * attI[c] + spj * attJ[c];
                    pkp[h] = f2bf(spj);
                }
                const unsigned p = (unsigned)(e0 + q * 4 + reg);  // sorted position
                *(ushort4*)&outj[p * 256 + dbase * 4] = pk;
            }
        }

        // ---- logit reduce + BN + exp + denom ----
#pragma unroll
        for (int off = 1; off < 16; off <<= 1) {
#pragma unroll
            for (int a = 0; a < 4; ++a)
#pragma unroll
                for (int b = 0; b < 4; ++b)
                    lg[a][b] += __shfl_xor(lg[a][b], off, 64);
        }
        float exv[4][4];
#pragma unroll
        for (int reg = 0; reg < 4; ++reg)
#pragma unroll
            for (int h = 0; h < 4; ++h)
                exv[reg][h] = __expf(softplus_f(fmaf(lg[reg][h], bnsc[h], bnsh[h])));

        // target-node ids for this quad's 4 edges (shfl while ALL lanes active)
        int iis[4];
#pragma unroll
        for (int reg = 0; reg < 4; ++reg)
            iis[reg] = __shfl(ei, q * 4 + reg, 16);

        if (r < 4) {  // lane r handles head r for its quad's 4 edges
#pragma unroll
            for (int reg = 0; reg < 4; ++reg) {
                const int p = e0 + q * 4 + reg;      // sorted position
                expa[p * 4 + r] = exv[reg][r];
                atomicAdd(&denom[iis[reg] * 4 + r], exv[reg][r]);
            }
        }
    }
}

// ===== counting sort of edges by target node =====
__global__ __launch_bounds__(256)
void k_hist(const int* __restrict__ eidx, int* __restrict__ cnt) {
    const int e = blockIdx.x * 256 + threadIdx.x;
    if (e < NE) atomicAdd(&cnt[eidx[e]], 1);
}

// Single-block merged scan: thread t owns bins [25t, 25t+25) (1000 threads
// cover NN=25000). Local sum -> LDS scan of 1024 totals -> per-bin writeback.
__global__ __launch_bounds__(1024)
void k_scan(const int* __restrict__ cnt, int* __restrict__ offs,
            int* __restrict__ cursor) {
    __shared__ int s[1024];
    const int tid = threadIdx.x;
    const int lo = tid * 25;
    int loc[25];
    int sum = 0;
    if (lo < NN) {
#pragma unroll
        for (int i = 0; i < 25; ++i) {
            loc[i] = cnt[lo + i];
            sum += loc[i];
        }
    }
    s[tid] = sum;
    __syncthreads();
#pragma unroll
    for (int off = 1; off < 1024; off <<= 1) {
        int t = (tid >= off) ? s[tid - off] : 0;
        __syncthreads();
        s[tid] += t;
        __syncthreads();
    }
    if (lo < NN) {
        int running = s[tid] - sum;   // exclusive base of this thread's range
#pragma unroll
        for (int i = 0; i < 25; ++i) {
            offs[lo + i] = running;
            cursor[lo + i] = running;
            running += loc[i];
        }
    }
    if (tid == 0) offs[NN] = NE;
}

__global__ __launch_bounds__(256)
void k_place(const int* __restrict__ eidx, int* __restrict__ cursor,
             int* __restrict__ perm) {
    const int e = blockIdx.x * 256 + threadIdx.x;
    if (e < NE) {
        const int pos = atomicAdd(&cursor[eidx[e]], 1);
        perm[pos] = e;
    }
}

// One wave per node, lane = dim d. outj/expa stored in sorted position order
// -> pure sequential stream (no indirection, no atomics).
__global__ __launch_bounds__(256)
void k_aggr(const int* __restrict__ offs,
            const unsigned short* __restrict__ outj,
            const float* __restrict__ expa,
            const float* __restrict__ denom,
            const float* __restrict__ bias,
            float* __restrict__ out)
{
    const int n = blockIdx.x * 4 + (threadIdx.x >> 6);
    if (n >= NN) return;
    const int lane = threadIdx.x & 63;
    const int k0 = offs[n], k1 = offs[n + 1];
    const float4 dv = *(const float4*)&denom[n * 4];
    float num0 = 0.f, num1 = 0.f, num2 = 0.f, num3 = 0.f;
    for (int k = k0; k < k1; ++k) {
        const float4 ex = *(const float4*)&expa[k * 4];
        const ushort4 v = *(const ushort4*)&outj[((unsigned)k << 8) | (lane << 2)];
        num0 += ex.x * bf2f(v.x);
        num1 += ex.y * bf2f(v.y);
        num2 += ex.z * bf2f(v.z);
        num3 += ex.w * bf2f(v.w);
    }
    float r = 0.f;
    r += (dv.x > 0.f) ? num0 / dv.x : 0.f;
    r += (dv.y > 0.f) ? num1 / dv.y : 0.f;
    r += (dv.z > 0.f) ? num2 / dv.z : 0.f;
    r += (dv.w > 0.f) ? num3 / dv.w : 0.f;
    out[n * DD + lane] = 0.25f * r + bias[lane];
}

extern "C" void kernel_launch(void* const* d_in, const int* in_sizes, int n_in,
                              void* d_out, int out_size, void* d_ws, size_t ws_size,
                              hipStream_t stream)
{
    (void)in_sizes; (void)n_in; (void)out_size; (void)ws_size;
    const float* x    = (const float*)d_in[0];
    const float* ea   = (const float*)d_in[1];
    const float* W    = (const float*)d_in[2];
    const float* att  = (const float*)d_in[3];
    const float* bias = (const float*)d_in[4];
    const float* bn_g = (const float*)d_in[5];
    const float* bn_b = (const float*)d_in[6];
    const float* bn_m = (const float*)d_in[7];
    const float* bn_v = (const float*)d_in[8];
    const int*   eidx = (const int*)d_in[9];
    float* out = (float*)d_out;

    // ws layout: outj bf16 [E][64][4] (128 MB) | expa f32 [E][4] (4 MB) |
    //   denom f32 [N][4] | cnt [N] | offs [N+1] | cursor [N] | perm [E]
    char* ws = (char*)d_ws;
    unsigned short* outj = (unsigned short*)ws;
    float* expa  = (float*)(ws + (size_t)NE * 512);
    float* denom = (float*)(ws + (size_t)NE * 512 + (size_t)NE * 16);
    int*   cnt    = (int*)(denom + (size_t)NN * 4);
    int*   offs   = cnt + NN;
    int*   cursor = offs + NN + 1;
    int*   perm   = cursor + NN;

    // one memset covers denom (NN*4 floats) + cnt (NN ints), adjacent
    hipMemsetAsync(denom, 0, (size_t)NN * 5 * sizeof(int), stream);

    k_hist <<<dim3((NE + 255) / 256), dim3(256), 0, stream>>>(eidx, cnt);
    k_scan <<<dim3(1), dim3(1024), 0, stream>>>(cnt, offs, cursor);
    k_place<<<dim3((NE + 255) / 256), dim3(256), 0, stream>>>(eidx, cursor, perm);

    k_edge<<<dim3(512), dim3(1024), 0, stream>>>(
        x, ea, W, att, bn_g, bn_b, bn_m, bn_v, eidx, perm, outj, expa, denom);

    k_aggr<<<dim3((NN + 3) / 4), dim3(256), 0, stream>>>(
        offs, outj, expa, denom, bias, out);
}